// Round 5
// baseline (8497.712 us; speedup 1.0000x reference)
//
#include <hip/hip_runtime.h>
#include <hip/hip_bf16.h>

typedef __bf16 bf16x8 __attribute__((ext_vector_type(8)));
typedef float f32x4 __attribute__((ext_vector_type(4)));

__device__ __forceinline__ float b2f(ushort u){
  union { uint u; float f; } x; x.u = ((uint)u) << 16; return x.f;
}
__device__ __forceinline__ ushort f2b(float f){
  union { float f; uint u; } x; x.f = f;
  uint r = x.u + 0x7fff + ((x.u >> 16) & 1);
  return (ushort)(r >> 16);
}
__device__ __forceinline__ uint pack_bf2(float a, float b){
  return (uint)f2b(a) | ((uint)f2b(b) << 16);
}
__device__ __forceinline__ float gelu_exact(float v){
  return 0.5f * v * (1.0f + erff(v * 0.70710678118654752f));
}

// ---------------------------------------------------------------------------
// 64x64-tile MFMA bf16 GEMM: C = scale*(A@W + bias) + resid, optional gelu.
// A: [M,K] f32 (AF32=1) or bf16 (AF32=0) row-major. W: f32, row stride ldw.
// bias/resid/Cf: f32. Cb: bf16. M,N mult of 64; K mult of 32.
// ---------------------------------------------------------------------------
template<int AF32, int ACT>
__global__ __launch_bounds__(256) void gemm_kernel(
    const void* __restrict__ Av, const float* __restrict__ W, int ldw,
    const float* __restrict__ bias, const float* residf,
    float* Cf, ushort* Cb,
    int M, int N, int K, float scale)
{
  __shared__ __align__(16) ushort Al[64*40];
  __shared__ __align__(16) ushort Bl[64*40];
  const int nb = N >> 6;
  const int rb = blockIdx.x / nb, cb = blockIdx.x % nb;
  const int tid = threadIdx.x;
  const int w = tid >> 6, l = tid & 63;
  f32x4 acc[4];
#pragma unroll
  for(int i=0;i<4;i++) acc[i] = (f32x4){0.f,0.f,0.f,0.f};
  const int ar = tid >> 2, ai = (tid & 3) << 3;
  const int bk = tid >> 3, bn = (tid & 7) << 3;
  for(int kb = 0; kb < K; kb += 32){
    uint4 au;
    if(AF32){
      const float* Ap = (const float*)Av + (size_t)(rb*64 + ar)*K + kb + ai;
      float4 f0 = *(const float4*)Ap;
      float4 f1 = *(const float4*)(Ap + 4);
      au.x = pack_bf2(f0.x,f0.y); au.y = pack_bf2(f0.z,f0.w);
      au.z = pack_bf2(f1.x,f1.y); au.w = pack_bf2(f1.z,f1.w);
    } else {
      au = *(const uint4*)((const ushort*)Av + (size_t)(rb*64 + ar)*K + kb + ai);
    }
    const float* Wp = W + (size_t)(kb + bk)*ldw + cb*64 + bn;
    float4 w0 = *(const float4*)Wp;
    float4 w1 = *(const float4*)(Wp + 4);
    ushort bs[8];
    bs[0]=f2b(w0.x); bs[1]=f2b(w0.y); bs[2]=f2b(w0.z); bs[3]=f2b(w0.w);
    bs[4]=f2b(w1.x); bs[5]=f2b(w1.y); bs[6]=f2b(w1.z); bs[7]=f2b(w1.w);
    __syncthreads();
    *(uint4*)&Al[ar*40 + ai] = au;
#pragma unroll
    for(int i=0;i<8;i++) Bl[(bn+i)*40 + bk] = bs[i];   // transposed: [n][k]
    __syncthreads();
    bf16x8 af = *(const bf16x8*)&Al[(w*16 + (l&15))*40 + (l>>4)*8];
#pragma unroll
    for(int c4=0;c4<4;c4++){
      bf16x8 bfv = *(const bf16x8*)&Bl[(c4*16 + (l&15))*40 + (l>>4)*8];
      acc[c4] = __builtin_amdgcn_mfma_f32_16x16x32_bf16(af, bfv, acc[c4], 0,0,0);
    }
  }
#pragma unroll
  for(int c4=0;c4<4;c4++){
#pragma unroll
    for(int r=0;r<4;r++){
      int row = rb*64 + w*16 + (l>>4)*4 + r;
      int col = cb*64 + c4*16 + (l&15);
      size_t idx = (size_t)row*N + col;
      float vv = acc[c4][r];
      if(bias) vv += bias[col];
      vv *= scale;
      if(residf) vv += residf[idx];
      if(ACT) vv = gelu_exact(vv);
      if(Cf) Cf[idx] = vv;
      if(Cb) Cb[idx] = f2b(vv);
    }
  }
}

// ---------------------------------------------------------------------------
// Causal self-attention: one WG per (b, head, 16-row q-block). bf16 in/out.
// LDS ~51 KB.
// ---------------------------------------------------------------------------
__global__ __launch_bounds__(256) void attn_kernel(const ushort* __restrict__ Q,
    const ushort* __restrict__ K, const ushort* __restrict__ V, ushort* __restrict__ O)
{
  __shared__ float s[16*520];
  __shared__ float kt[64*66];
  __shared__ float rowm[16], rowr[16], redx[256];
  const int bid = blockIdx.x;
  const int qb = bid & 31, h = (bid>>5)&3, b = bid>>7;
  const int tid = threadIdx.x;
  const int qi = tid >> 4, jj = tid & 15;
  const int qrow = qb*16 + qi;
  float qreg[64];
  {
    const ushort* qp = Q + ((size_t)(b*512 + qrow))*256 + h*64;
#pragma unroll
    for(int d=0; d<64; d++) qreg[d] = b2f(qp[d])*0.125f;
  }
  const int ntile = (qb*16 + 79) >> 6;
  for(int jt=0; jt<ntile; jt++){
    {
      int jr = tid >> 2, d0 = (tid & 3) << 4;
      const ushort* kp = K + ((size_t)(b*512 + jt*64 + jr))*256 + h*64 + d0;
#pragma unroll
      for(int i=0;i<16;i++) kt[jr*66 + d0 + i] = b2f(kp[i]);
    }
    __syncthreads();
#pragma unroll
    for(int jl=0;jl<4;jl++){
      int jloc = jj*4 + jl;
      int j = jt*64 + jloc;
      float a = 0.f;
#pragma unroll
      for(int d=0; d<64; d++) a += qreg[d]*kt[jloc*66 + d];
      s[qi*520 + j] = (j <= qrow) ? a : -1e30f;
    }
    __syncthreads();
  }
  const int nj = ntile*64;
  float m = -1e30f;
  for(int j=jj; j<nj; j+=16) m = fmaxf(m, s[qi*520 + j]);
  redx[jj*16 + qi] = m;
  __syncthreads();
  if(tid < 16){
    float mm = -1e30f;
#pragma unroll
    for(int k2=0;k2<16;k2++) mm = fmaxf(mm, redx[k2*16 + tid]);
    rowm[tid] = mm;
  }
  __syncthreads();
  float mrow = rowm[qi];
  float ssum = 0.f;
  for(int j=jj; j<nj; j+=16){
    float e = __expf(s[qi*520+j] - mrow);
    s[qi*520+j] = e; ssum += e;
  }
  redx[jj*16 + qi] = ssum;
  __syncthreads();
  if(tid < 16){
    float t2 = 0.f;
#pragma unroll
    for(int k2=0;k2<16;k2++) t2 += redx[k2*16 + tid];
    rowr[tid] = 1.0f/t2;
  }
  const int dd = jj;
  float acc4[4] = {0,0,0,0};
  for(int jt=0; jt<ntile; jt++){
    __syncthreads();
    {
      int jr = tid >> 2, d0 = (tid & 3) << 4;
      const ushort* vp = V + ((size_t)(b*512 + jt*64 + jr))*256 + h*64 + d0;
#pragma unroll
      for(int i=0;i<16;i++) kt[jr*66 + d0 + i] = b2f(vp[i]);
    }
    __syncthreads();
#pragma unroll
    for(int jl=0;jl<64;jl++){
      float p = s[qi*520 + jt*64 + jl];
#pragma unroll
      for(int i=0;i<4;i++) acc4[i] += p*kt[jl*66 + dd*4 + i];
    }
  }
  float rr = rowr[qi];
  ushort* op = O + ((size_t)(b*512 + qrow))*256 + h*64 + dd*4;
#pragma unroll
  for(int i=0;i<4;i++) op[i] = f2b(acc4[i]*rr);
}

// ---------------------------------------------------------------------------
// Row LayerNorm over 256 cols. One wave per row. f32 in; f32 and/or bf16 out.
// ---------------------------------------------------------------------------
__global__ __launch_bounds__(256) void ln_kernel(const float* __restrict__ in,
    const float* __restrict__ g, const float* __restrict__ be,
    float* outf, ushort* outb)
{
  int row = blockIdx.x*4 + (threadIdx.x>>6);
  int lane = threadIdx.x & 63;
  size_t idx = (size_t)row*256 + lane*4;
  float4 v = *(const float4*)(in + idx);
  float s1 = v.x+v.y+v.z+v.w;
  float s2 = v.x*v.x + v.y*v.y + v.z*v.z + v.w*v.w;
#pragma unroll
  for(int off=32; off; off>>=1){ s1 += __shfl_xor(s1,off); s2 += __shfl_xor(s2,off); }
  float mu = s1*(1.f/256.f);
  float var = s2*(1.f/256.f) - mu*mu;
  float r = rsqrtf(var + 1e-5f);
  float vals[4] = {v.x,v.y,v.z,v.w};
  float4 o4; ushort4 ob;
  float* oo = (float*)&o4; ushort* obp = (ushort*)&ob;
#pragma unroll
  for(int i=0;i<4;i++){
    int d = lane*4 + i;
    float y = (vals[i]-mu)*r*g[d] + be[d];
    oo[i] = y; obp[i] = f2b(y);
  }
  if(outf) *(float4*)(outf+idx) = o4;
  if(outb) *(ushort4*)(outb+idx) = ob;
}

// guid = h0 @ sp_w + sp_b  ([16,256] f32)
__global__ void guid_kernel(const float* __restrict__ h0, const float* __restrict__ spw,
                            const float* __restrict__ spb, float* __restrict__ guid)
{
  int b = blockIdx.x, c = threadIdx.x;
  float s = spb[c];
  for(int r=0;r<256;r++) s += h0[b*256+r]*spw[r*256+c];
  guid[b*256+c] = s;
}

// ffn_in = bf16(x1f + 0.3*guid[b]); x1f f32
__global__ void ffnin_kernel(const float* __restrict__ x1, const float* __restrict__ guid,
                             ushort* __restrict__ out)
{
  size_t base = ((size_t)blockIdx.x*256 + threadIdx.x)*8;
  int row = (int)(base >> 8); int bb = row >> 9; int c = (int)(base & 255);
  float4 v0 = *(const float4*)(x1 + base);
  float4 v1 = *(const float4*)(x1 + base + 4);
  const float* gp = guid + bb*256 + c;
  const float* xs = (const float*)&v0;
  ushort o[8];
#pragma unroll
  for(int i=0;i<4;i++) o[i] = f2b(xs[i] + 0.3f*gp[i]);
  const float* xs1 = (const float*)&v1;
#pragma unroll
  for(int i=0;i<4;i++) o[4+i] = f2b(xs1[i] + 0.3f*gp[4+i]);
  *(uint4*)(out + base) = *(uint4*)o;
}

// bo_f = ta_bo @ tr_w1[256:512, :]   ([512] f32)
__global__ void bo_kernel(const float* __restrict__ ta_bo, const float* __restrict__ tr_w1,
                          float* __restrict__ bo_f)
{
  int c = threadIdx.x;
  float s = 0.f;
  for(int m=0;m<256;m++) s += ta_bo[m]*tr_w1[(size_t)(256+m)*512 + c];
  bo_f[c] = s;
}

// ---------------------------------------------------------------------------
// Persistent scan kernel. 128 blocks x 512 threads.
// block = role*16 + b ; role 0..3 = X (attention head), role 4..7 = Y (MLP shard).
// All cross-WG data uses agent-scope atomics (flags rel/acq, payloads relaxed).
// k/v caches MUST be zero-initialized (phase C reads 8-wide blocks that can
// straddle the valid j<t boundary; 0*0=0 keeps them inert, stale-NaN*0 = NaN).
// ---------------------------------------------------------------------------
__global__ __launch_bounds__(512, 1) void scan_kernel(
    const float* __restrict__ x2all, const ushort* __restrict__ abf,
    const float* __restrict__ Wf, const float* __restrict__ bo_f,
    float* cbuf, float* dbuf, int* flags,
    ushort* kcache, ushort* vcache,
    const float* __restrict__ ta_wk, const float* __restrict__ ta_wv,
    const float* __restrict__ ta_wq,
    const float* __restrict__ ta_bk, const float* __restrict__ ta_bv,
    const float* __restrict__ ta_bq,
    const float* __restrict__ tr_w1, const float* __restrict__ tr_b1,
    const float* __restrict__ tr_w2, const float* __restrict__ tr_b2,
    const float* __restrict__ ln3_g, const float* __restrict__ ln3_b,
    const float* __restrict__ ln4_g, const float* __restrict__ ln4_b,
    const float* __restrict__ h0, float* __restrict__ out_h)
{
  __shared__ float red[1536];
  __shared__ float pbuf[512];
  __shared__ float hbuf[256];
  __shared__ float xbuf[256];   // X: x2_t ; Y: a_bf_t
  __shared__ float qbufS[64];
  __shared__ float misc[32];
  __shared__ float glbuf[128];

  const int tid = threadIdx.x;
  const int bid = blockIdx.x;
  const int b = bid & 15;
  const int role = bid >> 4;

  if(role < 4){
    // ================= X: attention head hd =================
    const int hd = role;
    const int bh = b*4 + hd;
    ushort* kc  = kcache + (size_t)bh*512*64;   // [j][d]
    ushort* vcT = vcache + (size_t)bh*64*512;   // [d][j]
    const int c = tid & 63, r8 = tid >> 6;
    float wkf[32], wvf[32], wqf[32];
#pragma unroll
    for(int i=0;i<32;i++){
      int row = r8*32 + i;
      wkf[i] = ta_wk[row*256 + hd*64 + c];
      wvf[i] = ta_wv[row*256 + hd*64 + c];
      wqf[i] = ta_wq[row*256 + hd*64 + c];
    }
    float prbias = 0.f;
    if(tid < 192){
      int grp = tid >> 6, d = tid & 63;
      prbias = (grp==0) ? ta_bk[hd*64+d]
             : (grp==1) ? ta_bv[hd*64+d]
             :            ta_bq[hd*64+d];
    }
    float b2r=0, g3r=0, b3r=0;
    if(tid < 256){
      b2r = tr_b2[tid]; g3r = ln3_g[tid]; b3r = ln3_b[tid];
      hbuf[tid] = h0[b*256 + tid];
    }
    __syncthreads();

#pragma clang loop unroll(disable)
    for(int t=0;t<512;t++){
      if(t > 0){
        if(tid < 256) xbuf[tid] = x2all[((size_t)(b*512 + t))*256 + tid];
        __syncthreads();
        // combined matvec: k,v from h_{t-1}; q from x2_t
        {
          float sk=0.f, sv=0.f, sq=0.f;
#pragma unroll
          for(int i=0;i<32;i++){
            float hv = hbuf[r8*32+i], xv = xbuf[r8*32+i];
            sk += hv*wkf[i]; sv += hv*wvf[i]; sq += xv*wqf[i];
          }
          red[r8*64 + c] = sk;
          red[512 + r8*64 + c] = sv;
          red[1024 + r8*64 + c] = sq;
        }
        __syncthreads();
        if(tid < 192){
          int grp = tid >> 6, d = tid & 63;
          float val = prbias;
#pragma unroll
          for(int i=0;i<8;i++) val += red[grp*512 + i*64 + d];
          if(grp == 0)      kc[(size_t)(t-1)*64 + d] = f2b(val);
          else if(grp == 1) vcT[(size_t)d*512 + (t-1)] = f2b(val);
          else              qbufS[d] = val*0.125f;
        }
        __syncthreads();
        // scores for j<t, softmax
        const int j = tid;
        float sc = -3.0e38f;
        if(j < t){
          const ushort* kr = kc + (size_t)j*64;
          float a = 0.f;
#pragma unroll
          for(int q8=0;q8<8;q8++){
            uint4 kk = *(const uint4*)(kr + q8*8);
            const uint* kw = (const uint*)&kk;
#pragma unroll
            for(int p=0;p<4;p++){
              a += qbufS[q8*8+2*p]   * b2f((ushort)(kw[p] & 0xffff));
              a += qbufS[q8*8+2*p+1] * b2f((ushort)(kw[p] >> 16));
            }
          }
          sc = a;
        }
        float wm = sc;
#pragma unroll
        for(int off=32; off; off>>=1) wm = fmaxf(wm, __shfl_xor(wm, off));
        if((tid&63)==0) misc[tid>>6] = wm;
        __syncthreads();
        float gm = misc[0];
#pragma unroll
        for(int i=1;i<8;i++) gm = fmaxf(gm, misc[i]);
        float e = (j < t) ? __expf(sc - gm) : 0.f;
        pbuf[j] = e;
        float wsum = e;
#pragma unroll
        for(int off=32; off; off>>=1) wsum += __shfl_xor(wsum, off);
        if((tid&63)==0) misc[8 + (tid>>6)] = wsum;
        __syncthreads();
        float gs = misc[8];
#pragma unroll
        for(int i=1;i<8;i++) gs += misc[8+i];
        float rsum = 1.0f / gs;
        // ctx = sum_j p_j * v_j   (zero-initialized cache makes tail blocks inert)
        {
          const int d = tid & 63, g = tid >> 6;
          float part = 0.f;
          const ushort* vr = vcT + (size_t)d*512 + g*64;
#pragma unroll
          for(int m8=0;m8<8;m8++){
            int j0 = g*64 + m8*8;
            if(j0 < t){
              uint4 vv = *(const uint4*)(vr + m8*8);
              const uint* vw = (const uint*)&vv;
#pragma unroll
              for(int p=0;p<4;p++){
                part += pbuf[j0+2*p]   * b2f((ushort)(vw[p] & 0xffff));
                part += pbuf[j0+2*p+1] * b2f((ushort)(vw[p] >> 16));
              }
            }
          }
          red[g*64 + d] = part;
        }
        __syncthreads();
        if(tid < 64){
          float cv = 0.f;
#pragma unroll
          for(int g2=0;g2<8;g2++) cv += red[g2*64 + tid];
          __hip_atomic_store(&cbuf[b*256 + hd*64 + tid], cv*rsum,
                             __ATOMIC_RELAXED, __HIP_MEMORY_SCOPE_AGENT);
        }
        __syncthreads();
        if(tid==0)
          __hip_atomic_store(&flags[bh], t, __ATOMIC_RELEASE, __HIP_MEMORY_SCOPE_AGENT);
      } // t>0

      // wait for 4 delta partials from Y
      if(tid < 4){
        while(__hip_atomic_load(&flags[64 + b*4 + tid], __ATOMIC_ACQUIRE, __HIP_MEMORY_SCOPE_AGENT) < t+1)
          __builtin_amdgcn_s_sleep(2);
      }
      __syncthreads();
      // combine: h = LN3(h + 0.5*(sum partials + tr_b2))
      float v = 0.f;
      if(tid < 256){
        float dsum = b2r;
#pragma unroll
        for(int i=0;i<4;i++)
          dsum += __hip_atomic_load(&dbuf[(b*4+i)*256 + tid],
                                    __ATOMIC_RELAXED, __HIP_MEMORY_SCOPE_AGENT);
        v = hbuf[tid] + 0.5f*dsum;
      }
      float s1 = v, s2 = v*v;
#pragma unroll
      for(int off=32; off; off>>=1){ s1 += __shfl_xor(s1,off); s2 += __shfl_xor(s2,off); }
      if((tid&63)==0){ misc[16 + (tid>>6)] = s1; misc[24 + (tid>>6)] = s2; }
      __syncthreads();
      float mu=0.f, qq=0.f;
#pragma unroll
      for(int i=0;i<8;i++){ mu += misc[16+i]; qq += misc[24+i]; }
      mu *= (1.f/256.f); qq = qq*(1.f/256.f) - mu*mu;
      float rstd = rsqrtf(qq + 1e-5f);
      if(tid < 256) hbuf[tid] = (v - mu)*rstd*g3r + b3r;
      __syncthreads();
    } // t loop

    if(hd == 0){
      float v2 = (tid<256) ? hbuf[tid] : 0.f;
      float s1 = v2, s2 = v2*v2;
#pragma unroll
      for(int off=32; off; off>>=1){ s1 += __shfl_xor(s1,off); s2 += __shfl_xor(s2,off); }
      if((tid&63)==0){ misc[16+(tid>>6)] = s1; misc[24+(tid>>6)] = s2; }
      __syncthreads();
      float mu=0.f, qq=0.f;
#pragma unroll
      for(int i=0;i<8;i++){ mu += misc[16+i]; qq += misc[24+i]; }
      mu *= (1.f/256.f); qq = qq*(1.f/256.f) - mu*mu;
      float rstd = rsqrtf(qq + 1e-5f);
      if(tid<256)
        out_h[b*256 + tid] = (v2-mu)*rstd*ln4_g[tid] + ln4_b[tid];
    }
  } else {
    // ================= Y: MLP shard ish =================
    const int ish = role - 4;
    const int ccol = tid & 127, r4 = tid >> 7;
    float wfr[64], w1t[64];
#pragma unroll
    for(int rr=0; rr<64; rr++){
      wfr[rr] = Wf[(size_t)(r4*64 + rr)*512 + ish*128 + ccol];
      w1t[rr] = tr_w1[(size_t)(r4*64 + rr)*512 + ish*128 + ccol];
    }
    const int dcol = tid & 255, c2 = tid >> 8;
    float w2r[64];
#pragma unroll
    for(int cc=0; cc<64; cc++)
      w2r[cc] = tr_w2[(size_t)(ish*128 + c2*64 + cc)*256 + dcol];
    float bor = 0.f, b1r = 0.f;
    if(tid < 128){
      bor = bo_f[ish*128 + tid];
      b1r = tr_b1[ish*128 + tid];
    }
    __syncthreads();

#pragma clang loop unroll(disable)
    for(int t=0;t<512;t++){
      if(tid < 256) xbuf[tid] = b2f(abf[((size_t)(b*512 + t))*256 + tid]);
      __syncthreads();
      // U partial (independent of ctx — off critical path)
      {
        float up = 0.f;
#pragma unroll
        for(int rr=0; rr<64; rr++) up += xbuf[r4*64 + rr]*w1t[rr];
        red[512 + r4*128 + ccol] = up;
      }
      if(t > 0 && tid < 4){
        while(__hip_atomic_load(&flags[b*4 + tid], __ATOMIC_ACQUIRE, __HIP_MEMORY_SCOPE_AGENT) < t)
          __builtin_amdgcn_s_sleep(2);
      }
      __syncthreads();
      if(t > 0 && tid < 256)
        hbuf[tid] = __hip_atomic_load(&cbuf[b*256 + tid],
                                      __ATOMIC_RELAXED, __HIP_MEMORY_SCOPE_AGENT);
      __syncthreads();
      float part = 0.f;
      if(t > 0){
#pragma unroll
        for(int rr=0; rr<64; rr++) part += hbuf[r4*64 + rr]*wfr[rr];
      }
      red[r4*128 + ccol] = part;
      __syncthreads();
      if(tid < 128){
        float Uv = b1r;
#pragma unroll
        for(int i=0;i<4;i++) Uv += red[512 + i*128 + tid];
        float g1 = Uv;
        if(t > 0){
          g1 += bor;
#pragma unroll
          for(int i=0;i<4;i++) g1 += red[i*128 + tid];
        }
        glbuf[tid] = gelu_exact(g1);
      }
      __syncthreads();
      {
        float dp = 0.f;
#pragma unroll
        for(int cc=0; cc<64; cc++) dp += glbuf[c2*64 + cc]*w2r[cc];
        red[c2*256 + dcol] = dp;
      }
      __syncthreads();
      if(tid < 256)
        __hip_atomic_store(&dbuf[(b*4+ish)*256 + tid], red[tid] + red[256+tid],
                           __ATOMIC_RELAXED, __HIP_MEMORY_SCOPE_AGENT);
      __syncthreads();
      if(tid == 0)
        __hip_atomic_store(&flags[64 + b*4 + ish], t+1, __ATOMIC_RELEASE, __HIP_MEMORY_SCOPE_AGENT);
    }
  }
}

// ---------------------------------------------------------------------------
// Workspace layout (bytes). TOTAL = 29 MiB.
// ---------------------------------------------------------------------------
#define OFF_FLAGS ((size_t)0)          //  512 B
#define OFF_BOF   ((size_t)1024)       //  2 KB  f32[512]
#define OFF_CBUF  ((size_t)4096)       // 16 KB  f32[16*256]
#define OFF_DBUF  ((size_t)20480)      // 64 KB  f32[16*4*256]
#define OFF_GUID  ((size_t)86016)      // 16 KB  f32[4096]
#define OFF_WF    ((size_t)131072)     // 512 KB f32[256*512]
#define OFF_Z1    ((size_t)(1u<<20))   // 4 MB
#define OFF_Z2    ((size_t)(5u<<20))   // 4 MB
#define OFF_Z3    ((size_t)(9u<<20))   // 4 MB
#define OFF_Z4    ((size_t)(13u<<20))  // 4 MB
#define OFF_M     ((size_t)(17u<<20))  // 12 MB  -> total 29 MB

extern "C" void kernel_launch(void* const* d_in, const int* in_sizes, int n_in,
                              void* d_out, int out_size, void* d_ws, size_t ws_size,
                              hipStream_t stream)
{
  const float* x     = (const float*)d_in[0];
  const float* h0    = (const float*)d_in[1];
  const float* sa_wq = (const float*)d_in[2];
  const float* sa_wk = (const float*)d_in[3];
  const float* sa_wv = (const float*)d_in[4];
  const float* sa_wo = (const float*)d_in[5];
  const float* sa_bq = (const float*)d_in[6];
  const float* sa_bk = (const float*)d_in[7];
  const float* sa_bv = (const float*)d_in[8];
  const float* sa_bo = (const float*)d_in[9];
  const float* f_w1  = (const float*)d_in[10];
  const float* f_b1  = (const float*)d_in[11];
  const float* f_w2  = (const float*)d_in[12];
  const float* f_b2  = (const float*)d_in[13];
  const float* ta_wq = (const float*)d_in[14];
  const float* ta_wk = (const float*)d_in[15];
  const float* ta_wv = (const float*)d_in[16];
  const float* ta_wo = (const float*)d_in[17];
  const float* ta_bq = (const float*)d_in[18];
  const float* ta_bk = (const float*)d_in[19];
  const float* ta_bv = (const float*)d_in[20];
  const float* ta_bo = (const float*)d_in[21];
  const float* tr_w1 = (const float*)d_in[22];
  const float* tr_b1 = (const float*)d_in[23];
  const float* tr_w2 = (const float*)d_in[24];
  const float* tr_b2 = (const float*)d_in[25];
  const float* ps_w  = (const float*)d_in[26];
  const float* ps_b  = (const float*)d_in[27];
  const float* sp_w  = (const float*)d_in[28];
  const float* sp_b  = (const float*)d_in[29];
  const float* ln1_g = (const float*)d_in[30];
  const float* ln1_b = (const float*)d_in[31];
  const float* ln2_g = (const float*)d_in[32];
  const float* ln2_b = (const float*)d_in[33];
  const float* ln3_g = (const float*)d_in[34];
  const float* ln3_b = (const float*)d_in[35];
  const float* ln4_g = (const float*)d_in[36];
  const float* ln4_b = (const float*)d_in[37];

  char* ws = (char*)d_ws;
  int*    flags = (int*)   (ws + OFF_FLAGS);
  float*  bo_f  = (float*) (ws + OFF_BOF);
  float*  cbuf  = (float*) (ws + OFF_CBUF);
  float*  dbuf  = (float*) (ws + OFF_DBUF);
  float*  guid  = (float*) (ws + OFF_GUID);
  float*  Wff   = (float*) (ws + OFF_WF);
  ushort* qb    = (ushort*)(ws + OFF_Z1);
  ushort* kb    = (ushort*)(ws + OFF_Z2);
  ushort* vb    = (ushort*)(ws + OFF_Z3);
  ushort* attnb = (ushort*)(ws + OFF_Z4);
  float*  x0pre = (float*) (ws + OFF_Z1);   // Z1+Z2, 8 MB
  float*  x1f   = (float*) (ws + OFF_Z3);   // Z3+Z4, 8 MB
  ushort* ffnb  = (ushort*)(ws + OFF_M);            // 4 MB
  ushort* mid   = (ushort*)(ws + OFF_M + (4u<<20)); // 8 MB [8192,512] bf16
  float*  x2pre = (float*) (ws + OFF_Z1);   // Z1+Z2, 8 MB
  ushort* abf   = (ushort*)(ws + OFF_Z4);   // 4 MB
  ushort* kc    = (ushort*)(ws + OFF_Z1);   // scan k cache, 4 MB
  ushort* vc    = (ushort*)(ws + OFF_Z2);   // scan v cache, 4 MB
  float*  outb  = (float*)d_out;
  float*  out_h = outb + (out_size - 4096);

  hipMemsetAsync(flags, 0, 512, stream);

  // ===== parallel prefix =====
  gemm_kernel<1,0><<<512, 256, 0, stream>>>(x, sa_wq, 256, sa_bq, nullptr, nullptr, qb, 8192,256,256, 1.0f);
  gemm_kernel<1,0><<<512, 256, 0, stream>>>(x, sa_wk, 256, sa_bk, nullptr, nullptr, kb, 8192,256,256, 1.0f);
  gemm_kernel<1,0><<<512, 256, 0, stream>>>(x, sa_wv, 256, sa_bv, nullptr, nullptr, vb, 8192,256,256, 1.0f);
  attn_kernel<<<2048, 256, 0, stream>>>(qb, kb, vb, attnb);
  gemm_kernel<0,0><<<512, 256, 0, stream>>>(attnb, sa_wo, 256, sa_bo, x, x0pre, nullptr, 8192,256,256, 1.0f);
  ln_kernel<<<2048, 256, 0, stream>>>(x0pre, ln1_g, ln1_b, x1f, nullptr);
  guid_kernel<<<16, 256, 0, stream>>>(h0, sp_w, sp_b, guid);
  ffnin_kernel<<<1024, 256, 0, stream>>>(x1f, guid, ffnb);
  // FFN in two K-halves over N=1024 (mid is [8192,512] per half)
  gemm_kernel<0,1><<<1024, 256, 0, stream>>>(ffnb, f_w1, 1024, f_b1, nullptr, nullptr, mid, 8192,512,256, 1.0f);
  gemm_kernel<0,0><<<512, 256, 0, stream>>>(mid, f_w2, 256, f_b2, x1f, x2pre, nullptr, 8192,256,512, 1.0f);
  gemm_kernel<0,1><<<1024, 256, 0, stream>>>(ffnb, f_w1 + 512, 1024, f_b1 + 512, nullptr, nullptr, mid, 8192,512,256, 1.0f);
  gemm_kernel<0,0><<<512, 256, 0, stream>>>(mid, f_w2 + (size_t)512*256, 256, nullptr, x2pre, x2pre, nullptr, 8192,256,512, 1.0f);
  ln_kernel<<<2048, 256, 0, stream>>>(x2pre, ln2_g, ln2_b, outb, nullptr);   // output 0 (f32)

  // ===== scan precompute =====
  // abf = bf16(x2 + 0.3*(x2@ps_w + ps_b))
  gemm_kernel<1,0><<<512, 256, 0, stream>>>(outb, ps_w, 256, ps_b, outb, nullptr, abf, 8192,256,256, 0.3f);
  // Wf = ta_wo @ tr_w1[256:512,:]
  gemm_kernel<1,0><<<32, 256, 0, stream>>>(ta_wo, tr_w1 + (size_t)256*512, 512, nullptr, nullptr, Wff, nullptr, 256,512,256, 1.0f);
  bo_kernel<<<1, 512, 0, stream>>>(ta_bo, tr_w1, bo_f);

  // Zero k/v caches (Z1+Z2): x2pre is dead after ln2. bf16 0x0000 = 0.0 keeps
  // phase-C straddling block reads inert (stale f32 residue decodes to NaN bf16).
  hipMemsetAsync(ws + OFF_Z1, 0, (size_t)(8u<<20), stream);

  // ===== sequential scan (persistent pipelined kernel) =====
  scan_kernel<<<128, 512, 0, stream>>>(outb, abf, Wff, bo_f, cbuf, dbuf, flags, kc, vc,
                                       ta_wk, ta_wv, ta_wq, ta_bk, ta_bv, ta_bq,
                                       tr_w1, tr_b1, tr_w2, tr_b2,
                                       ln3_g, ln3_b, ln4_g, ln4_b, h0, out_h);
}

// Round 6
// 5131.582 us; speedup vs baseline: 1.6560x; 1.6560x over previous
//
#include <hip/hip_runtime.h>
#include <hip/hip_bf16.h>

typedef __bf16 bf16x8 __attribute__((ext_vector_type(8)));
typedef float f32x4 __attribute__((ext_vector_type(4)));

__device__ __forceinline__ float b2f(ushort u){
  union { uint u; float f; } x; x.u = ((uint)u) << 16; return x.f;
}
__device__ __forceinline__ ushort f2b(float f){
  union { float f; uint u; } x; x.f = f;
  uint r = x.u + 0x7fff + ((x.u >> 16) & 1);
  return (ushort)(r >> 16);
}
__device__ __forceinline__ uint pack_bf2(float a, float b){
  return (uint)f2b(a) | ((uint)f2b(b) << 16);
}
__device__ __forceinline__ float lo16(uint u){ union{uint a;float f;}x; x.a=u<<16; return x.f; }
__device__ __forceinline__ float hi16(uint u){ union{uint a;float f;}x; x.a=u&0xffff0000u; return x.f; }
__device__ __forceinline__ float gelu_exact(float v){
  return 0.5f * v * (1.0f + erff(v * 0.70710678118654752f));
}

// ---------------------------------------------------------------------------
// 64x64-tile MFMA bf16 GEMM (unchanged from round 5)
// ---------------------------------------------------------------------------
template<int AF32, int ACT>
__global__ __launch_bounds__(256) void gemm_kernel(
    const void* __restrict__ Av, const float* __restrict__ W, int ldw,
    const float* __restrict__ bias, const float* residf,
    float* Cf, ushort* Cb,
    int M, int N, int K, float scale)
{
  __shared__ __align__(16) ushort Al[64*40];
  __shared__ __align__(16) ushort Bl[64*40];
  const int nb = N >> 6;
  const int rb = blockIdx.x / nb, cb = blockIdx.x % nb;
  const int tid = threadIdx.x;
  const int w = tid >> 6, l = tid & 63;
  f32x4 acc[4];
#pragma unroll
  for(int i=0;i<4;i++) acc[i] = (f32x4){0.f,0.f,0.f,0.f};
  const int ar = tid >> 2, ai = (tid & 3) << 3;
  const int bk = tid >> 3, bn = (tid & 7) << 3;
  for(int kb = 0; kb < K; kb += 32){
    uint4 au;
    if(AF32){
      const float* Ap = (const float*)Av + (size_t)(rb*64 + ar)*K + kb + ai;
      float4 f0 = *(const float4*)Ap;
      float4 f1 = *(const float4*)(Ap + 4);
      au.x = pack_bf2(f0.x,f0.y); au.y = pack_bf2(f0.z,f0.w);
      au.z = pack_bf2(f1.x,f1.y); au.w = pack_bf2(f1.z,f1.w);
    } else {
      au = *(const uint4*)((const ushort*)Av + (size_t)(rb*64 + ar)*K + kb + ai);
    }
    const float* Wp = W + (size_t)(kb + bk)*ldw + cb*64 + bn;
    float4 w0 = *(const float4*)Wp;
    float4 w1 = *(const float4*)(Wp + 4);
    ushort bs[8];
    bs[0]=f2b(w0.x); bs[1]=f2b(w0.y); bs[2]=f2b(w0.z); bs[3]=f2b(w0.w);
    bs[4]=f2b(w1.x); bs[5]=f2b(w1.y); bs[6]=f2b(w1.z); bs[7]=f2b(w1.w);
    __syncthreads();
    *(uint4*)&Al[ar*40 + ai] = au;
#pragma unroll
    for(int i=0;i<8;i++) Bl[(bn+i)*40 + bk] = bs[i];
    __syncthreads();
    bf16x8 af = *(const bf16x8*)&Al[(w*16 + (l&15))*40 + (l>>4)*8];
#pragma unroll
    for(int c4=0;c4<4;c4++){
      bf16x8 bfv = *(const bf16x8*)&Bl[(c4*16 + (l&15))*40 + (l>>4)*8];
      acc[c4] = __builtin_amdgcn_mfma_f32_16x16x32_bf16(af, bfv, acc[c4], 0,0,0);
    }
  }
#pragma unroll
  for(int c4=0;c4<4;c4++){
#pragma unroll
    for(int r=0;r<4;r++){
      int row = rb*64 + w*16 + (l>>4)*4 + r;
      int col = cb*64 + c4*16 + (l&15);
      size_t idx = (size_t)row*N + col;
      float vv = acc[c4][r];
      if(bias) vv += bias[col];
      vv *= scale;
      if(residf) vv += residf[idx];
      if(ACT) vv = gelu_exact(vv);
      if(Cf) Cf[idx] = vv;
      if(Cb) Cb[idx] = f2b(vv);
    }
  }
}

// ---------------------------------------------------------------------------
// Causal self-attention (unchanged from round 5)
// ---------------------------------------------------------------------------
__global__ __launch_bounds__(256) void attn_kernel(const ushort* __restrict__ Q,
    const ushort* __restrict__ K, const ushort* __restrict__ V, ushort* __restrict__ O)
{
  __shared__ float s[16*520];
  __shared__ float kt[64*66];
  __shared__ float rowm[16], rowr[16], redx[256];
  const int bid = blockIdx.x;
  const int qb = bid & 31, h = (bid>>5)&3, b = bid>>7;
  const int tid = threadIdx.x;
  const int qi = tid >> 4, jj = tid & 15;
  const int qrow = qb*16 + qi;
  float qreg[64];
  {
    const ushort* qp = Q + ((size_t)(b*512 + qrow))*256 + h*64;
#pragma unroll
    for(int d=0; d<64; d++) qreg[d] = b2f(qp[d])*0.125f;
  }
  const int ntile = (qb*16 + 79) >> 6;
  for(int jt=0; jt<ntile; jt++){
    {
      int jr = tid >> 2, d0 = (tid & 3) << 4;
      const ushort* kp = K + ((size_t)(b*512 + jt*64 + jr))*256 + h*64 + d0;
#pragma unroll
      for(int i=0;i<16;i++) kt[jr*66 + d0 + i] = b2f(kp[i]);
    }
    __syncthreads();
#pragma unroll
    for(int jl=0;jl<4;jl++){
      int jloc = jj*4 + jl;
      int j = jt*64 + jloc;
      float a = 0.f;
#pragma unroll
      for(int d=0; d<64; d++) a += qreg[d]*kt[jloc*66 + d];
      s[qi*520 + j] = (j <= qrow) ? a : -1e30f;
    }
    __syncthreads();
  }
  const int nj = ntile*64;
  float m = -1e30f;
  for(int j=jj; j<nj; j+=16) m = fmaxf(m, s[qi*520 + j]);
  redx[jj*16 + qi] = m;
  __syncthreads();
  if(tid < 16){
    float mm = -1e30f;
#pragma unroll
    for(int k2=0;k2<16;k2++) mm = fmaxf(mm, redx[k2*16 + tid]);
    rowm[tid] = mm;
  }
  __syncthreads();
  float mrow = rowm[qi];
  float ssum = 0.f;
  for(int j=jj; j<nj; j+=16){
    float e = __expf(s[qi*520+j] - mrow);
    s[qi*520+j] = e; ssum += e;
  }
  redx[jj*16 + qi] = ssum;
  __syncthreads();
  if(tid < 16){
    float t2 = 0.f;
#pragma unroll
    for(int k2=0;k2<16;k2++) t2 += redx[k2*16 + tid];
    rowr[tid] = 1.0f/t2;
  }
  const int dd = jj;
  float acc4[4] = {0,0,0,0};
  for(int jt=0; jt<ntile; jt++){
    __syncthreads();
    {
      int jr = tid >> 2, d0 = (tid & 3) << 4;
      const ushort* vp = V + ((size_t)(b*512 + jt*64 + jr))*256 + h*64 + d0;
#pragma unroll
      for(int i=0;i<16;i++) kt[jr*66 + d0 + i] = b2f(vp[i]);
    }
    __syncthreads();
#pragma unroll
    for(int jl=0;jl<64;jl++){
      float p = s[qi*520 + jt*64 + jl];
#pragma unroll
      for(int i=0;i<4;i++) acc4[i] += p*kt[jl*66 + dd*4 + i];
    }
  }
  float rr = rowr[qi];
  ushort* op = O + ((size_t)(b*512 + qrow))*256 + h*64 + dd*4;
#pragma unroll
  for(int i=0;i<4;i++) op[i] = f2b(acc4[i]*rr);
}

// ---------------------------------------------------------------------------
// LayerNorm / small kernels (unchanged)
// ---------------------------------------------------------------------------
__global__ __launch_bounds__(256) void ln_kernel(const float* __restrict__ in,
    const float* __restrict__ g, const float* __restrict__ be,
    float* outf, ushort* outb)
{
  int row = blockIdx.x*4 + (threadIdx.x>>6);
  int lane = threadIdx.x & 63;
  size_t idx = (size_t)row*256 + lane*4;
  float4 v = *(const float4*)(in + idx);
  float s1 = v.x+v.y+v.z+v.w;
  float s2 = v.x*v.x + v.y*v.y + v.z*v.z + v.w*v.w;
#pragma unroll
  for(int off=32; off; off>>=1){ s1 += __shfl_xor(s1,off); s2 += __shfl_xor(s2,off); }
  float mu = s1*(1.f/256.f);
  float var = s2*(1.f/256.f) - mu*mu;
  float r = rsqrtf(var + 1e-5f);
  float vals[4] = {v.x,v.y,v.z,v.w};
  float4 o4; ushort4 ob;
  float* oo = (float*)&o4; ushort* obp = (ushort*)&ob;
#pragma unroll
  for(int i=0;i<4;i++){
    int d = lane*4 + i;
    float y = (vals[i]-mu)*r*g[d] + be[d];
    oo[i] = y; obp[i] = f2b(y);
  }
  if(outf) *(float4*)(outf+idx) = o4;
  if(outb) *(ushort4*)(outb+idx) = ob;
}

__global__ void guid_kernel(const float* __restrict__ h0, const float* __restrict__ spw,
                            const float* __restrict__ spb, float* __restrict__ guid)
{
  int b = blockIdx.x, c = threadIdx.x;
  float s = spb[c];
  for(int r=0;r<256;r++) s += h0[b*256+r]*spw[r*256+c];
  guid[b*256+c] = s;
}

__global__ void ffnin_kernel(const float* __restrict__ x1, const float* __restrict__ guid,
                             ushort* __restrict__ out)
{
  size_t base = ((size_t)blockIdx.x*256 + threadIdx.x)*8;
  int row = (int)(base >> 8); int bb = row >> 9; int c = (int)(base & 255);
  float4 v0 = *(const float4*)(x1 + base);
  float4 v1 = *(const float4*)(x1 + base + 4);
  const float* gp = guid + bb*256 + c;
  const float* xs = (const float*)&v0;
  ushort o[8];
#pragma unroll
  for(int i=0;i<4;i++) o[i] = f2b(xs[i] + 0.3f*gp[i]);
  const float* xs1 = (const float*)&v1;
#pragma unroll
  for(int i=0;i<4;i++) o[4+i] = f2b(xs1[i] + 0.3f*gp[4+i]);
  *(uint4*)(out + base) = *(uint4*)o;
}

__global__ void bo_kernel(const float* __restrict__ ta_bo, const float* __restrict__ tr_w1,
                          float* __restrict__ bo_f)
{
  int c = threadIdx.x;
  float s = 0.f;
  for(int m=0;m<256;m++) s += ta_bo[m]*tr_w1[(size_t)(256+m)*512 + c];
  bo_f[c] = s;
}

// ---------------------------------------------------------------------------
// Persistent scan kernel. 128 blocks x 512 threads.
// block = role*16 + b ; role 0..3 = X (attention head), role 4..7 = Y (MLP shard).
// XCD-locality-adaptive sync:
//  - one-time handshake publishes each block's XCC_ID (agent atomics);
//  - co-located pairs (shared XCD L2): plain payload stores + __syncthreads
//    (drains vmcnt) + volatile (sc0, L1-bypass) flag store/poll + volatile
//    payload reads. Zero sc1 traffic per step.
//  - remote pairs: shadow flags with agent release/acquire (buffer_wbl2 /
//    buffer_inv) — correct under any placement.
// Flags: [0..63] fastX, [64..127] fastY, [128..191] shadowX, [192..255] shadowY,
//        [256..383] xcc table. All zeroed before launch.
// ---------------------------------------------------------------------------
__global__ __launch_bounds__(512, 1) void scan_kernel(
    const float* __restrict__ x2all, const ushort* __restrict__ abf,
    const float* __restrict__ Wf, const float* __restrict__ bo_f,
    float* cbuf, float* dbuf, int* flags,
    ushort* kcache, ushort* vcache,
    const float* __restrict__ ta_wk, const float* __restrict__ ta_wv,
    const float* __restrict__ ta_wq,
    const float* __restrict__ ta_bk, const float* __restrict__ ta_bv,
    const float* __restrict__ ta_bq,
    const float* __restrict__ tr_w1, const float* __restrict__ tr_b1,
    const float* __restrict__ tr_w2, const float* __restrict__ tr_b2,
    const float* __restrict__ ln3_g, const float* __restrict__ ln3_b,
    const float* __restrict__ ln4_g, const float* __restrict__ ln4_b,
    const float* __restrict__ h0, float* __restrict__ out_h)
{
  __shared__ float red[1536];
  __shared__ float pbuf[512];
  __shared__ float hbuf[256];
  __shared__ float xbuf[256];
  __shared__ float qbufS[64];
  __shared__ float misc[32];
  __shared__ float glbuf[128];
  __shared__ int cp_same[4];

  const int tid = threadIdx.x;
  const int bid = blockIdx.x;
  const int b = bid & 15;
  const int role = bid >> 4;

  // ---- one-time XCD handshake ----
  int myxcc;
  asm volatile("s_getreg_b32 %0, hwreg(HW_REG_XCC_ID)" : "=s"(myxcc));
  if(tid == 0)
    __hip_atomic_store(&flags[256 + bid], myxcc + 1, __ATOMIC_RELEASE, __HIP_MEMORY_SCOPE_AGENT);
  if(tid < 4){
    int cbid = (role < 4) ? (64 + tid*16 + b) : (tid*16 + b);
    int v;
    while((v = __hip_atomic_load(&flags[256 + cbid], __ATOMIC_ACQUIRE, __HIP_MEMORY_SCOPE_AGENT)) == 0)
      __builtin_amdgcn_s_sleep(8);
    cp_same[tid] = ((v - 1) == myxcc);
  }
  __syncthreads();
  const int anyrem = !(cp_same[0] && cp_same[1] && cp_same[2] && cp_same[3]);
  const int cs0 = cp_same[0], cs1 = cp_same[1], cs2 = cp_same[2], cs3 = cp_same[3];

  if(role < 4){
    // ================= X: attention head hd =================
    const int hd = role;
    const int bh = b*4 + hd;
    ushort* kc  = kcache + (size_t)bh*512*64;   // [j][d]
    ushort* vcT = vcache + (size_t)bh*64*512;   // [d][j]
    const int c = tid & 63, r8 = tid >> 6;
    uint wkp[16], wvp[16], wqp[16];
#pragma unroll
    for(int i=0;i<16;i++){
      int r0 = r8*32 + 2*i, r1 = r0 + 1;
      wkp[i] = pack_bf2(ta_wk[r0*256 + hd*64 + c], ta_wk[r1*256 + hd*64 + c]);
      wvp[i] = pack_bf2(ta_wv[r0*256 + hd*64 + c], ta_wv[r1*256 + hd*64 + c]);
      wqp[i] = pack_bf2(ta_wq[r0*256 + hd*64 + c], ta_wq[r1*256 + hd*64 + c]);
    }
    float prbias = 0.f;
    if(tid < 192){
      int grp = tid >> 6, d = tid & 63;
      prbias = (grp==0) ? ta_bk[hd*64+d]
             : (grp==1) ? ta_bv[hd*64+d]
             :            ta_bq[hd*64+d];
    }
    float b2r=0, g3r=0, b3r=0;
    if(tid < 256){
      b2r = tr_b2[tid]; g3r = ln3_g[tid]; b3r = ln3_b[tid];
      hbuf[tid] = h0[b*256 + tid];
    }
    __syncthreads();

#pragma clang loop unroll(disable)
    for(int t=0;t<512;t++){
      if(t > 0){
        if(tid < 256) xbuf[tid] = x2all[((size_t)(b*512 + t))*256 + tid];
        __syncthreads();
        // combined matvec: k,v from h_{t-1}; q from x2_t
        {
          float sk=0.f, sv=0.f, sq=0.f;
#pragma unroll
          for(int i=0;i<16;i++){
            float ha = hbuf[r8*32+2*i], hb2 = hbuf[r8*32+2*i+1];
            float xa = xbuf[r8*32+2*i], xb2 = xbuf[r8*32+2*i+1];
            sk += ha*lo16(wkp[i]) + hb2*hi16(wkp[i]);
            sv += ha*lo16(wvp[i]) + hb2*hi16(wvp[i]);
            sq += xa*lo16(wqp[i]) + xb2*hi16(wqp[i]);
          }
          red[r8*64 + c] = sk;
          red[512 + r8*64 + c] = sv;
          red[1024 + r8*64 + c] = sq;
        }
        __syncthreads();
        if(tid < 192){
          int grp = tid >> 6, d = tid & 63;
          float val = prbias;
#pragma unroll
          for(int i=0;i<8;i++) val += red[grp*512 + i*64 + d];
          if(grp == 0)      kc[(size_t)(t-1)*64 + d] = f2b(val);
          else if(grp == 1) vcT[(size_t)d*512 + (t-1)] = f2b(val);
          else              qbufS[d] = val*0.125f;
        }
        __syncthreads();
        // scores for j<t, softmax
        const int j = tid;
        float sc = -3.0e38f;
        if(j < t){
          const ushort* kr = kc + (size_t)j*64;
          float a = 0.f;
#pragma unroll
          for(int q8=0;q8<8;q8++){
            uint4 kk = *(const uint4*)(kr + q8*8);
            const uint* kw = (const uint*)&kk;
#pragma unroll
            for(int p=0;p<4;p++){
              a += qbufS[q8*8+2*p]   * b2f((ushort)(kw[p] & 0xffff));
              a += qbufS[q8*8+2*p+1] * b2f((ushort)(kw[p] >> 16));
            }
          }
          sc = a;
        }
        float wm = sc;
#pragma unroll
        for(int off=32; off; off>>=1) wm = fmaxf(wm, __shfl_xor(wm, off));
        if((tid&63)==0) misc[tid>>6] = wm;
        __syncthreads();
        float gm = misc[0];
#pragma unroll
        for(int i=1;i<8;i++) gm = fmaxf(gm, misc[i]);
        float e = (j < t) ? __expf(sc - gm) : 0.f;
        pbuf[j] = e;
        float wsum = e;
#pragma unroll
        for(int off=32; off; off>>=1) wsum += __shfl_xor(wsum, off);
        if((tid&63)==0) misc[8 + (tid>>6)] = wsum;
        __syncthreads();
        float gs = misc[8];
#pragma unroll
        for(int i=1;i<8;i++) gs += misc[8+i];
        float rsum = 1.0f / gs;
        // ctx = sum_j p_j * v_j
        {
          const int d = tid & 63, g = tid >> 6;
          float part = 0.f;
          const ushort* vr = vcT + (size_t)d*512 + g*64;
#pragma unroll
          for(int m8=0;m8<8;m8++){
            int j0 = g*64 + m8*8;
            if(j0 < t){
              uint4 vv = *(const uint4*)(vr + m8*8);
              const uint* vw = (const uint*)&vv;
#pragma unroll
              for(int p=0;p<4;p++){
                part += pbuf[j0+2*p]   * b2f((ushort)(vw[p] & 0xffff));
                part += pbuf[j0+2*p+1] * b2f((ushort)(vw[p] >> 16));
              }
            }
          }
          red[g*64 + d] = part;
        }
        __syncthreads();
        if(tid < 64){
          float cv = 0.f;
#pragma unroll
          for(int g2=0;g2<8;g2++) cv += red[g2*64 + tid];
          cbuf[b*256 + hd*64 + tid] = cv*rsum;   // plain store -> local L2
        }
        __syncthreads();   // drains each wave's stores (vmcnt) before flag
        if(tid==0){
          *(volatile int*)&flags[bh] = t;        // fast flag (sc0)
          if(anyrem)
            __hip_atomic_store(&flags[128 + bh], t, __ATOMIC_RELEASE, __HIP_MEMORY_SCOPE_AGENT);
        }
      } // t>0

      // wait for 4 delta partials from Y
      if(tid < 4){
        int fast = (tid==0)?cs0:(tid==1)?cs1:(tid==2)?cs2:cs3;
        if(fast){
          while(*(volatile int*)&flags[64 + b*4 + tid] < t+1) __builtin_amdgcn_s_sleep(1);
        } else {
          while(__hip_atomic_load(&flags[192 + b*4 + tid], __ATOMIC_RELAXED, __HIP_MEMORY_SCOPE_AGENT) < t+1)
            __builtin_amdgcn_s_sleep(2);
        }
      }
      __syncthreads();
      if(anyrem) __builtin_amdgcn_fence(__ATOMIC_ACQUIRE, "agent");
      // combine: h = LN3(h + 0.5*(sum partials + tr_b2))
      float v = 0.f;
      if(tid < 256){
        float dsum = b2r;
#pragma unroll
        for(int i=0;i<4;i++)
          dsum += *(volatile float*)&dbuf[(b*4+i)*256 + tid];
        v = hbuf[tid] + 0.5f*dsum;
      }
      float s1 = v, s2 = v*v;
#pragma unroll
      for(int off=32; off; off>>=1){ s1 += __shfl_xor(s1,off); s2 += __shfl_xor(s2,off); }
      if((tid&63)==0){ misc[16 + (tid>>6)] = s1; misc[24 + (tid>>6)] = s2; }
      __syncthreads();
      float mu=0.f, qq=0.f;
#pragma unroll
      for(int i=0;i<8;i++){ mu += misc[16+i]; qq += misc[24+i]; }
      mu *= (1.f/256.f); qq = qq*(1.f/256.f) - mu*mu;
      float rstd = rsqrtf(qq + 1e-5f);
      if(tid < 256) hbuf[tid] = (v - mu)*rstd*g3r + b3r;
      __syncthreads();
    } // t loop

    if(hd == 0){
      float v2 = (tid<256) ? hbuf[tid] : 0.f;
      float s1 = v2, s2 = v2*v2;
#pragma unroll
      for(int off=32; off; off>>=1){ s1 += __shfl_xor(s1,off); s2 += __shfl_xor(s2,off); }
      if((tid&63)==0){ misc[16+(tid>>6)] = s1; misc[24+(tid>>6)] = s2; }
      __syncthreads();
      float mu=0.f, qq=0.f;
#pragma unroll
      for(int i=0;i<8;i++){ mu += misc[16+i]; qq += misc[24+i]; }
      mu *= (1.f/256.f); qq = qq*(1.f/256.f) - mu*mu;
      float rstd = rsqrtf(qq + 1e-5f);
      if(tid<256)
        out_h[b*256 + tid] = (v2-mu)*rstd*ln4_g[tid] + ln4_b[tid];
    }
  } else {
    // ================= Y: MLP shard ish =================
    const int ish = role - 4;
    const int ccol = tid & 127, r4 = tid >> 7;
    uint wfp[32], w1p[32];
#pragma unroll
    for(int i=0;i<32;i++){
      int r0 = r4*64 + 2*i, r1 = r0 + 1;
      wfp[i] = pack_bf2(Wf[(size_t)r0*512 + ish*128 + ccol], Wf[(size_t)r1*512 + ish*128 + ccol]);
      w1p[i] = pack_bf2(tr_w1[(size_t)r0*512 + ish*128 + ccol], tr_w1[(size_t)r1*512 + ish*128 + ccol]);
    }
    const int dcol = tid & 255, c2 = tid >> 8;
    uint w2p[32];
#pragma unroll
    for(int i=0;i<32;i++){
      int c0 = ish*128 + c2*64 + 2*i, c1 = c0 + 1;
      w2p[i] = pack_bf2(tr_w2[(size_t)c0*256 + dcol], tr_w2[(size_t)c1*256 + dcol]);
    }
    float bor = 0.f, b1r = 0.f;
    if(tid < 128){
      bor = bo_f[ish*128 + tid];
      b1r = tr_b1[ish*128 + tid];
    }
    __syncthreads();

#pragma clang loop unroll(disable)
    for(int t=0;t<512;t++){
      if(tid < 256) xbuf[tid] = b2f(abf[((size_t)(b*512 + t))*256 + tid]);
      __syncthreads();
      // U partial (independent of ctx — off critical path)
      {
        float up = 0.f;
#pragma unroll
        for(int i=0;i<32;i++)
          up += xbuf[r4*64+2*i]*lo16(w1p[i]) + xbuf[r4*64+2*i+1]*hi16(w1p[i]);
        red[512 + r4*128 + ccol] = up;
      }
      if(t > 0 && tid < 4){
        int fast = (tid==0)?cs0:(tid==1)?cs1:(tid==2)?cs2:cs3;
        if(fast){
          while(*(volatile int*)&flags[b*4 + tid] < t) __builtin_amdgcn_s_sleep(1);
        } else {
          while(__hip_atomic_load(&flags[128 + b*4 + tid], __ATOMIC_RELAXED, __HIP_MEMORY_SCOPE_AGENT) < t)
            __builtin_amdgcn_s_sleep(2);
        }
      }
      __syncthreads();
      if(t > 0){
        if(anyrem) __builtin_amdgcn_fence(__ATOMIC_ACQUIRE, "agent");
        if(tid < 256) hbuf[tid] = *(volatile float*)&cbuf[b*256 + tid];
      }
      __syncthreads();
      float part = 0.f;
      if(t > 0){
#pragma unroll
        for(int i=0;i<32;i++)
          part += hbuf[r4*64+2*i]*lo16(wfp[i]) + hbuf[r4*64+2*i+1]*hi16(wfp[i]);
      }
      red[r4*128 + ccol] = part;
      __syncthreads();
      if(tid < 128){
        float Uv = b1r;
#pragma unroll
        for(int i=0;i<4;i++) Uv += red[512 + i*128 + tid];
        float g1 = Uv;
        if(t > 0){
          g1 += bor;
#pragma unroll
          for(int i=0;i<4;i++) g1 += red[i*128 + tid];
        }
        glbuf[tid] = gelu_exact(g1);
      }
      __syncthreads();
      {
        float dp = 0.f;
#pragma unroll
        for(int i=0;i<32;i++)
          dp += glbuf[c2*64+2*i]*lo16(w2p[i]) + glbuf[c2*64+2*i+1]*hi16(w2p[i]);
        red[c2*256 + dcol] = dp;
      }
      __syncthreads();
      if(tid < 256)
        dbuf[(b*4+ish)*256 + tid] = red[tid] + red[256+tid];   // plain store
      __syncthreads();   // drain stores before flag
      if(tid == 0){
        *(volatile int*)&flags[64 + b*4 + ish] = t+1;          // fast flag
        if(anyrem)
          __hip_atomic_store(&flags[192 + b*4 + ish], t+1, __ATOMIC_RELEASE, __HIP_MEMORY_SCOPE_AGENT);
      }
    }
  }
}

// ---------------------------------------------------------------------------
// Workspace layout (bytes). TOTAL = 29 MiB.
// ---------------------------------------------------------------------------
#define OFF_FLAGS ((size_t)0)          //  2 KB  (fast/shadow flags + xcc table)
#define OFF_BOF   ((size_t)2048)       //  2 KB  f32[512]
#define OFF_CBUF  ((size_t)4096)       // 16 KB  f32[16*256]
#define OFF_DBUF  ((size_t)20480)      // 64 KB  f32[16*4*256]
#define OFF_GUID  ((size_t)86016)      // 16 KB  f32[4096]
#define OFF_WF    ((size_t)131072)     // 512 KB f32[256*512]
#define OFF_Z1    ((size_t)(1u<<20))   // 4 MB
#define OFF_Z2    ((size_t)(5u<<20))   // 4 MB
#define OFF_Z3    ((size_t)(9u<<20))   // 4 MB
#define OFF_Z4    ((size_t)(13u<<20))  // 4 MB
#define OFF_M     ((size_t)(17u<<20))  // 12 MB  -> total 29 MB

extern "C" void kernel_launch(void* const* d_in, const int* in_sizes, int n_in,
                              void* d_out, int out_size, void* d_ws, size_t ws_size,
                              hipStream_t stream)
{
  const float* x     = (const float*)d_in[0];
  const float* h0    = (const float*)d_in[1];
  const float* sa_wq = (const float*)d_in[2];
  const float* sa_wk = (const float*)d_in[3];
  const float* sa_wv = (const float*)d_in[4];
  const float* sa_wo = (const float*)d_in[5];
  const float* sa_bq = (const float*)d_in[6];
  const float* sa_bk = (const float*)d_in[7];
  const float* sa_bv = (const float*)d_in[8];
  const float* sa_bo = (const float*)d_in[9];
  const float* f_w1  = (const float*)d_in[10];
  const float* f_b1  = (const float*)d_in[11];
  const float* f_w2  = (const float*)d_in[12];
  const float* f_b2  = (const float*)d_in[13];
  const float* ta_wq = (const float*)d_in[14];
  const float* ta_wk = (const float*)d_in[15];
  const float* ta_wv = (const float*)d_in[16];
  const float* ta_wo = (const float*)d_in[17];
  const float* ta_bq = (const float*)d_in[18];
  const float* ta_bk = (const float*)d_in[19];
  const float* ta_bv = (const float*)d_in[20];
  const float* ta_bo = (const float*)d_in[21];
  const float* tr_w1 = (const float*)d_in[22];
  const float* tr_b1 = (const float*)d_in[23];
  const float* tr_w2 = (const float*)d_in[24];
  const float* tr_b2 = (const float*)d_in[25];
  const float* ps_w  = (const float*)d_in[26];
  const float* ps_b  = (const float*)d_in[27];
  const float* sp_w  = (const float*)d_in[28];
  const float* sp_b  = (const float*)d_in[29];
  const float* ln1_g = (const float*)d_in[30];
  const float* ln1_b = (const float*)d_in[31];
  const float* ln2_g = (const float*)d_in[32];
  const float* ln2_b = (const float*)d_in[33];
  const float* ln3_g = (const float*)d_in[34];
  const float* ln3_b = (const float*)d_in[35];
  const float* ln4_g = (const float*)d_in[36];
  const float* ln4_b = (const float*)d_in[37];

  char* ws = (char*)d_ws;
  int*    flags = (int*)   (ws + OFF_FLAGS);
  float*  bo_f  = (float*) (ws + OFF_BOF);
  float*  cbuf  = (float*) (ws + OFF_CBUF);
  float*  dbuf  = (float*) (ws + OFF_DBUF);
  float*  guid  = (float*) (ws + OFF_GUID);
  float*  Wff   = (float*) (ws + OFF_WF);
  ushort* qb    = (ushort*)(ws + OFF_Z1);
  ushort* kb    = (ushort*)(ws + OFF_Z2);
  ushort* vb    = (ushort*)(ws + OFF_Z3);
  ushort* attnb = (ushort*)(ws + OFF_Z4);
  float*  x0pre = (float*) (ws + OFF_Z1);   // Z1+Z2, 8 MB
  float*  x1f   = (float*) (ws + OFF_Z3);   // Z3+Z4, 8 MB
  ushort* ffnb  = (ushort*)(ws + OFF_M);            // 4 MB
  ushort* mid   = (ushort*)(ws + OFF_M + (4u<<20)); // 8 MB
  float*  x2pre = (float*) (ws + OFF_Z1);   // Z1+Z2, 8 MB
  ushort* abf   = (ushort*)(ws + OFF_Z4);   // 4 MB
  ushort* kc    = (ushort*)(ws + OFF_Z1);   // scan k cache, 4 MB
  ushort* vc    = (ushort*)(ws + OFF_Z2);   // scan v cache, 4 MB
  float*  outb  = (float*)d_out;
  float*  out_h = outb + (out_size - 4096);

  hipMemsetAsync(flags, 0, 2048, stream);

  // ===== parallel prefix =====
  gemm_kernel<1,0><<<512, 256, 0, stream>>>(x, sa_wq, 256, sa_bq, nullptr, nullptr, qb, 8192,256,256, 1.0f);
  gemm_kernel<1,0><<<512, 256, 0, stream>>>(x, sa_wk, 256, sa_bk, nullptr, nullptr, kb, 8192,256,256, 1.0f);
  gemm_kernel<1,0><<<512, 256, 0, stream>>>(x, sa_wv, 256, sa_bv, nullptr, nullptr, vb, 8192,256,256, 1.0f);
  attn_kernel<<<2048, 256, 0, stream>>>(qb, kb, vb, attnb);
  gemm_kernel<0,0><<<512, 256, 0, stream>>>(attnb, sa_wo, 256, sa_bo, x, x0pre, nullptr, 8192,256,256, 1.0f);
  ln_kernel<<<2048, 256, 0, stream>>>(x0pre, ln1_g, ln1_b, x1f, nullptr);
  guid_kernel<<<16, 256, 0, stream>>>(h0, sp_w, sp_b, guid);
  ffnin_kernel<<<1024, 256, 0, stream>>>(x1f, guid, ffnb);
  gemm_kernel<0,1><<<1024, 256, 0, stream>>>(ffnb, f_w1, 1024, f_b1, nullptr, nullptr, mid, 8192,512,256, 1.0f);
  gemm_kernel<0,0><<<512, 256, 0, stream>>>(mid, f_w2, 256, f_b2, x1f, x2pre, nullptr, 8192,256,512, 1.0f);
  gemm_kernel<0,1><<<1024, 256, 0, stream>>>(ffnb, f_w1 + 512, 1024, f_b1 + 512, nullptr, nullptr, mid, 8192,512,256, 1.0f);
  gemm_kernel<0,0><<<512, 256, 0, stream>>>(mid, f_w2 + (size_t)512*256, 256, nullptr, x2pre, x2pre, nullptr, 8192,256,512, 1.0f);
  ln_kernel<<<2048, 256, 0, stream>>>(x2pre, ln2_g, ln2_b, outb, nullptr);   // output 0 (f32)

  // ===== scan precompute =====
  gemm_kernel<1,0><<<512, 256, 0, stream>>>(outb, ps_w, 256, ps_b, outb, nullptr, abf, 8192,256,256, 0.3f);
  gemm_kernel<1,0><<<32, 256, 0, stream>>>(ta_wo, tr_w1 + (size_t)256*512, 512, nullptr, nullptr, Wff, nullptr, 256,512,256, 1.0f);
  bo_kernel<<<1, 512, 0, stream>>>(ta_bo, tr_w1, bo_f);

  // Zero k/v caches (Z1+Z2): phase-C straddling reads must see 0.0 not stale f32.
  hipMemsetAsync(ws + OFF_Z1, 0, (size_t)(8u<<20), stream);

  // ===== sequential scan (persistent pipelined kernel) =====
  scan_kernel<<<128, 512, 0, stream>>>(outb, abf, Wff, bo_f, cbuf, dbuf, flags, kc, vc,
                                       ta_wk, ta_wv, ta_wq, ta_bk, ta_bv, ta_bq,
                                       tr_w1, tr_b1, tr_w2, tr_b2,
                                       ln3_g, ln3_b, ln4_g, ln4_b, h0, out_h);
}